// Round 6
// baseline (47.007 us; speedup 1.0000x reference)
//
#include <hip/hip_runtime.h>
#include <math.h>

// B=4, L=1024, C=128, D=64; rows = B*L = 4096
#define LL   1024
#define NROW 4096
#define DD   64
#define CC   128

// leaky(z) = C1*z + C2*|z|  (slope 0.01)
#define C1H 0.505f
#define C2H 0.495f

typedef short  bf16x8 __attribute__((ext_vector_type(8)));
typedef float  f32x4  __attribute__((ext_vector_type(4)));

static __device__ __forceinline__ unsigned short bf16rne(float f) {
  unsigned u = __float_as_uint(f);
  u += 0x7fffu + ((u >> 16) & 1u);
  return (unsigned short)(u >> 16);
}

static __device__ __forceinline__ void unpk(unsigned u, float& lo, float& hi) {
  lo = __uint_as_float(u << 16);
  hi = __uint_as_float(u & 0xffff0000u);
}

// force a block-uniform float into an SGPR
static __device__ __forceinline__ float rflf(float v) {
  return __uint_as_float(__builtin_amdgcn_readfirstlane(__float_as_uint(v)));
}

// ---------------------------------------------------------------------------
// k_proj: 8 rows/block, 256 threads; thread = (row-pair, d).
// Outputs:
//   glg   : gl bf16, granule-major [b][g=d/8][y] as uint4 (8 bf16 = d 8g..8g+7)
//   gr    : fp32 row-major
//   grT_bf: bf16 [b][d][y] for MFMA B-frags
//   AL/AR : fp32 row dots with a
// ---------------------------------------------------------------------------
__global__ __launch_bounds__(256) void k_proj(
    const float* __restrict__ q, const float* __restrict__ Wl,
    const float* __restrict__ Wr, const float* __restrict__ a,
    uint4* __restrict__ glg, float* __restrict__ gr,
    unsigned short* __restrict__ grT_bf,
    float* __restrict__ AL, float* __restrict__ AR) {
  const int bl0 = blockIdx.x * 8;        // 512 blocks, no batch straddle
  const int b = bl0 >> 10;
  const int t = threadIdx.x;
  __shared__ __align__(16) float qs[8 * CC];          // 4 KB
  __shared__ __align__(16) unsigned short trT[DD][8]; // 1 KB
  __shared__ __align__(16) unsigned short trL[8][DD]; // 1 KB

  ((float4*)qs)[t] = ((const float4*)(q + (size_t)bl0 * CC))[t];
  __syncthreads();

  const int rr = t >> 6;                 // 0..3 -> rows rr*2, rr*2+1
  const int d  = t & 63;
  const int r0 = rr * 2, r1 = rr * 2 + 1;
  const float* q0 = qs + r0 * CC;
  const float* q1 = qs + r1 * CC;

  float aL0 = 0, aL1 = 0, aR0 = 0, aR1 = 0;
  float bL0 = 0, bL1 = 0, bR0 = 0, bR1 = 0;
#pragma unroll 8
  for (int c = 0; c < CC; c += 2) {
    float wl0 = Wl[c * DD + d],       wr0 = Wr[c * DD + d];
    float wl1 = Wl[(c + 1) * DD + d], wr1 = Wr[(c + 1) * DD + d];
    aL0 = fmaf(q0[c], wl0, aL0);  bL0 = fmaf(q0[c + 1], wl1, bL0);
    aL1 = fmaf(q1[c], wl0, aL1);  bL1 = fmaf(q1[c + 1], wl1, bL1);
    aR0 = fmaf(q0[c], wr0, aR0);  bR0 = fmaf(q0[c + 1], wr1, bR0);
    aR1 = fmaf(q1[c], wr0, aR1);  bR1 = fmaf(q1[c + 1], wr1, bR1);
  }
  float gL0 = aL0 + bL0, gL1 = aL1 + bL1;
  float gR0 = aR0 + bR0, gR1 = aR1 + bR1;

  trL[r0][d] = bf16rne(gL0);
  trL[r1][d] = bf16rne(gL1);
  gr[(size_t)(bl0 + r0) * DD + d] = gR0;
  gr[(size_t)(bl0 + r1) * DD + d] = gR1;
  trT[d][r0] = bf16rne(gR0);
  trT[d][r1] = bf16rne(gR1);

  float av = a[d];
  float vL0 = av * gL0, vL1 = av * gL1, vR0 = av * gR0, vR1 = av * gR1;
#pragma unroll
  for (int off = 1; off < 64; off <<= 1) {
    vL0 += __shfl_xor(vL0, off, 64);
    vL1 += __shfl_xor(vL1, off, 64);
    vR0 += __shfl_xor(vR0, off, 64);
    vR1 += __shfl_xor(vR1, off, 64);
  }
  if (d == 0) {
    AL[bl0 + r0] = vL0; AL[bl0 + r1] = vL1;
    AR[bl0 + r0] = vR0; AR[bl0 + r1] = vR1;
  }
  __syncthreads();
  if (t < 64) {
    *(uint4*)&grT_bf[(((size_t)(b * 64 + t)) << 10) + (bl0 & 1023)] =
        *(const uint4*)&trT[t][0];
  } else if (t < 128) {
    int tt = t - 64;
    int r = tt >> 3, g = tt & 7;       // row r, granule g (d = 8g..8g+7)
    glg[(((size_t)(b * 8 + g)) << 10) + (bl0 & 1023) + r] =
        *(const uint4*)&trL[r][g * 8];
  }
}

// ---------------------------------------------------------------------------
// k_e: block = 4 x-rows, 256 threads, grid 1024.
//  pass 1 (lane-owns-y): gl from glg straight to VGPRs (coalesced, L2-hot);
//    gr & a snapshot into SGPRs via readfirstlane -> inner loop pure VALU.
//  softmax: exact 2-phase (shuffle + tiny LDS cross-wave reduce).
//  writes fp32 normalized scores (coalesced, L2-cached for k_pv).
// ---------------------------------------------------------------------------
__global__ __launch_bounds__(256, 4) void k_e(
    const uint4* __restrict__ glg, const float* __restrict__ gr,
    const float* __restrict__ AL, const float* __restrict__ AR,
    const float* __restrict__ a,
    float* __restrict__ scores) {
  const int bl0 = blockIdx.x * 4;        // 1024 blocks
  const int b = bl0 >> 10;
  const int t = threadIdx.x;
  const int w = t >> 6, l = t & 63;

  __shared__ float sRedM[4][4], sRedS[4][4];

  float pr[4];
#pragma unroll
  for (int x = 0; x < 4; ++x) pr[x] = C1H * rflf(AR[bl0 + x]);

  float alv[4];
#pragma unroll
  for (int yc = 0; yc < 4; ++yc) alv[yc] = AL[b * LL + yc * 256 + t];

  // ---- pass 1: e in registers, dblk-outer; gr/a in SGPRs ----
  float pacc[4][4];                      // [x][yc]
#pragma unroll
  for (int x = 0; x < 4; ++x)
#pragma unroll
    for (int yc = 0; yc < 4; ++yc) pacc[x][yc] = 0.f;

#pragma unroll
  for (int dblk = 0; dblk < 4; ++dblk) {
    // batched gl loads for this dblk (8 x uint4 = 32 VGPR, hoisted)
    uint4 gv[4][2];
#pragma unroll
    for (int yc = 0; yc < 4; ++yc)
#pragma unroll
      for (int g2 = 0; g2 < 2; ++g2)
        gv[yc][g2] = glg[(((size_t)(b * 8 + dblk * 2 + g2)) << 10) + yc * 256 + t];

    // snapshot a[dblk*16 .. +16) into 16 SGPRs
    float sa[16];
#pragma unroll
    for (int c4 = 0; c4 < 4; ++c4) {
      float4 v = *(const float4*)&a[dblk * 16 + c4 * 4];
      sa[c4 * 4 + 0] = rflf(v.x); sa[c4 * 4 + 1] = rflf(v.y);
      sa[c4 * 4 + 2] = rflf(v.z); sa[c4 * 4 + 3] = rflf(v.w);
    }
    // snapshot gr[x][dblk*16 .. +16) into 64 SGPRs
    float sgr[4][16];
#pragma unroll
    for (int x = 0; x < 4; ++x)
#pragma unroll
      for (int c4 = 0; c4 < 4; ++c4) {
        float4 v = *(const float4*)&gr[(size_t)(bl0 + x) * DD + dblk * 16 + c4 * 4];
        sgr[x][c4 * 4 + 0] = rflf(v.x); sgr[x][c4 * 4 + 1] = rflf(v.y);
        sgr[x][c4 * 4 + 2] = rflf(v.z); sgr[x][c4 * 4 + 3] = rflf(v.w);
      }

#pragma unroll
    for (int yc = 0; yc < 4; ++yc) {
      float glv[16];
      unpk(gv[yc][0].x, glv[0], glv[1]);   unpk(gv[yc][0].y, glv[2], glv[3]);
      unpk(gv[yc][0].z, glv[4], glv[5]);   unpk(gv[yc][0].w, glv[6], glv[7]);
      unpk(gv[yc][1].x, glv[8], glv[9]);   unpk(gv[yc][1].y, glv[10], glv[11]);
      unpk(gv[yc][1].z, glv[12], glv[13]); unpk(gv[yc][1].w, glv[14], glv[15]);
#pragma unroll
      for (int x = 0; x < 4; ++x) {
        float s = pacc[x][yc];
#pragma unroll
        for (int c = 0; c < 16; ++c)
          s = fmaf(fabsf(glv[c] + sgr[x][c]), sa[c], s);
        pacc[x][yc] = s;
      }
    }
  }

  float ev[4][4];
#pragma unroll
  for (int x = 0; x < 4; ++x)
#pragma unroll
    for (int yc = 0; yc < 4; ++yc)
      ev[x][yc] = fmaf(C2H, pacc[x][yc], pr[x] + C1H * alv[yc]);

  // ---- exact softmax: max phase ----
  float lm[4];
#pragma unroll
  for (int x = 0; x < 4; ++x)
    lm[x] = fmaxf(fmaxf(ev[x][0], ev[x][1]), fmaxf(ev[x][2], ev[x][3]));
#pragma unroll
  for (int off = 1; off < 64; off <<= 1) {
#pragma unroll
    for (int x = 0; x < 4; ++x) lm[x] = fmaxf(lm[x], __shfl_xor(lm[x], off, 64));
  }
  if (l == 0) {
#pragma unroll
    for (int x = 0; x < 4; ++x) sRedM[w][x] = lm[x];
  }
  __syncthreads();                       // barrier 1

  float mfin[4], lsum[4];
#pragma unroll
  for (int x = 0; x < 4; ++x)
    mfin[x] = fmaxf(fmaxf(sRedM[0][x], sRedM[1][x]),
                    fmaxf(sRedM[2][x], sRedM[3][x]));
#pragma unroll
  for (int x = 0; x < 4; ++x) {
    lsum[x] = 0.f;
#pragma unroll
    for (int yc = 0; yc < 4; ++yc) {
      ev[x][yc] = __expf(ev[x][yc] - mfin[x]);
      lsum[x] += ev[x][yc];
    }
  }
#pragma unroll
  for (int off = 1; off < 64; off <<= 1) {
#pragma unroll
    for (int x = 0; x < 4; ++x) lsum[x] += __shfl_xor(lsum[x], off, 64);
  }
  if (l == 0) {
#pragma unroll
    for (int x = 0; x < 4; ++x) sRedS[w][x] = lsum[x];
  }
  __syncthreads();                       // barrier 2

  float isv[4];
#pragma unroll
  for (int x = 0; x < 4; ++x)
    isv[x] = 1.0f / (sRedS[0][x] + sRedS[1][x] + sRedS[2][x] + sRedS[3][x]);

  // ---- normalized fp32 scores, coalesced ----
#pragma unroll
  for (int yc = 0; yc < 4; ++yc) {
    int y = yc * 256 + t;
#pragma unroll
    for (int x = 0; x < 4; ++x)
      scores[((size_t)(bl0 + x) << 10) + y] = ev[x][yc] * isv[x];
  }
}

// ---------------------------------------------------------------------------
// k_pv: 256 blocks x 512 threads, 16 x-rows per block (1 block/CU).
//  A-frags: read fp32 scores (L2-hot) -> bf16rne in-reg; all 16 MFMA rows
//  valid (m = x). B-frags from grT_bf. kc (32 chunks of K=32) split across
//  8 waves; cross-wave sum via LDS.
//  Lane mapping (validated R3-R5): A lane l holds A[m=l&15][k=(l>>4)*8+j];
//  B lane l holds B[k=(l>>4)*8+j][n=l&15]; D: row m=(l>>4)*4+i, col n=l&15.
// ---------------------------------------------------------------------------
__global__ __launch_bounds__(512) void k_pv(
    const float* __restrict__ scores, const unsigned short* __restrict__ grT_bf,
    float* __restrict__ yout) {
  const int bl0 = blockIdx.x * 16;       // 256 blocks, no batch straddle
  const int b = bl0 >> 10;
  const int t = threadIdx.x;             // 0..511
  const int w = t >> 6, l = t & 63;
  const int row16 = l & 15, hh = l >> 4; // hh 0..3

  __shared__ float sPV[8][4][16][17];    // [wave][nt][x][d-col], ~34.8 KB

  f32x4 acc[4] = {{0.f, 0.f, 0.f, 0.f}, {0.f, 0.f, 0.f, 0.f},
                  {0.f, 0.f, 0.f, 0.f}, {0.f, 0.f, 0.f, 0.f}};
  const size_t bnBase = ((size_t)b * 64) << 10;
  const float* arow = scores + ((size_t)(bl0 + row16) << 10);

#pragma unroll
  for (int kk = 0; kk < 4; ++kk) {
    const int kc = w + kk * 8;
    // A-frag: P[x=row16][kc*32 + hh*8 .. +8] fp32 -> bf16x8
    float4 f0 = *(const float4*)&arow[kc * 32 + hh * 8];
    float4 f1 = *(const float4*)&arow[kc * 32 + hh * 8 + 4];
    union { unsigned short us[8]; bf16x8 v; } af;
    af.us[0] = bf16rne(f0.x); af.us[1] = bf16rne(f0.y);
    af.us[2] = bf16rne(f0.z); af.us[3] = bf16rne(f0.w);
    af.us[4] = bf16rne(f1.x); af.us[5] = bf16rne(f1.y);
    af.us[6] = bf16rne(f1.z); af.us[7] = bf16rne(f1.w);
#pragma unroll
    for (int nt = 0; nt < 4; ++nt) {
      bf16x8 bfv = *(const bf16x8*)(grT_bf + bnBase +
                     (((size_t)(nt * 16 + row16)) << 10) + kc * 32 + hh * 8);
      acc[nt] = __builtin_amdgcn_mfma_f32_16x16x32_bf16(af.v, bfv, acc[nt], 0, 0, 0);
    }
  }

#pragma unroll
  for (int nt = 0; nt < 4; ++nt)
#pragma unroll
    for (int i = 0; i < 4; ++i)
      sPV[w][nt][hh * 4 + i][row16] = acc[nt][i];
  __syncthreads();

  // 1024 outputs (16 x * 64 d), 2 per thread
#pragma unroll
  for (int rep = 0; rep < 2; ++rep) {
    int o = t + rep * 512;
    int x = o >> 6, dcol = o & 63, nt = dcol >> 4, col = dcol & 15;
    float r = 0.f;
#pragma unroll
    for (int ww = 0; ww < 8; ++ww) r += sPV[ww][nt][x][col];
    yout[(size_t)(bl0 + x) * DD + dcol] = r;
  }
}

// ---------------------------------------------------------------------------
extern "C" void kernel_launch(void* const* d_in, const int* in_sizes, int n_in,
                              void* d_out, int out_size, void* d_ws, size_t ws_size,
                              hipStream_t stream) {
  const float* q  = (const float*)d_in[0];
  // d_in[1] = keys, d_in[2] = values: unused by the reference math
  const float* Wl = (const float*)d_in[3];
  const float* Wr = (const float*)d_in[4];
  const float* a  = (const float*)d_in[5];

  float* yout = (float*)d_out;                 // (4096, 64)
  float* esc  = yout + NROW * DD;              // (4096, 1024) scores

  float* ws = (float*)d_ws;
  float* gr = ws;                               // 4096*64 f32  (1 MB)
  float* AL = gr + NROW * DD;                   // 4096
  float* AR = AL + NROW;                        // 4096
  uint4* glg = (uint4*)(AR + NROW);             // 4096*8 uint4 (512 KB)
  unsigned short* grT_bf = (unsigned short*)(glg + (size_t)NROW * 8); // 512 KB

  k_proj<<<NROW / 8, 256, 0, stream>>>(q, Wl, Wr, a, glg, gr, grT_bf, AL, AR);
  k_e   <<<NROW / 4, 256, 0, stream>>>(glg, gr, AL, AR, a, esc);
  k_pv  <<<NROW / 16, 512, 0, stream>>>(esc, grT_bf, yout);
}

// Round 9
// 39.402 us; speedup vs baseline: 1.1930x; 1.1930x over previous
//
#include <hip/hip_runtime.h>
#include <math.h>

// B=4, L=1024, C=128, D=64; rows = B*L = 4096
#define LL   1024
#define NROW 4096
#define DD   64
#define CC   128

// leaky(z) = C1*z + C2*|z|  (slope 0.01)
#define C1H 0.505f
#define C2H 0.495f

typedef short    bf16x8 __attribute__((ext_vector_type(8)));
typedef float    f32x4  __attribute__((ext_vector_type(4)));
typedef _Float16 hf2    __attribute__((ext_vector_type(2)));

#if defined(__has_builtin)
#if __has_builtin(__builtin_amdgcn_fdot2)
#define HAS_FDOT2 1
#endif
#endif

static __device__ __forceinline__ unsigned short bf16rne(float f) {
  unsigned u = __float_as_uint(f);
  u += 0x7fffu + ((u >> 16) & 1u);
  return (unsigned short)(u >> 16);
}

static __device__ __forceinline__ unsigned rflu(unsigned v) {
  return __builtin_amdgcn_readfirstlane(v);
}
static __device__ __forceinline__ float rflf(float v) {
  return __uint_as_float(__builtin_amdgcn_readfirstlane(__float_as_uint(v)));
}

// acc += dot(|gl2 + gr2|, a2)  on packed f16 pairs, f32 accumulate
static __device__ __forceinline__ float dot2abs(unsigned glp, unsigned grp,
                                                unsigned ap, float acc) {
  union { unsigned u; hf2 h; } g1, g2, z, av;
  g1.u = glp; g2.u = grp; av.u = ap;
  z.h = g1.h + g2.h;           // v_pk_add_f16
  z.u &= 0x7fff7fffu;          // packed abs (1 v_and)
#ifdef HAS_FDOT2
  return __builtin_amdgcn_fdot2(z.h, av.h, acc, false);  // v_dot2_f32_f16
#else
  return fmaf((float)z.h.y, (float)av.h.y,
              fmaf((float)z.h.x, (float)av.h.x, acc));
#endif
}

// ---------------------------------------------------------------------------
// k_proj: 8 rows/block, 256 threads; thread = (row-pair, d).
// Outputs:
//   glg   : gl f16, granule-major [b][g=d/8][y] as uint4 (8 f16 = d 8g..8g+7)
//   gr16  : gr f16 row-major [row][d]
//   grT_bf: gr bf16 [b][d][y] for MFMA B-frags
//   AL/AR : fp32 row dots with a (exact, from fp32 g)
// ---------------------------------------------------------------------------
__global__ __launch_bounds__(256) void k_proj(
    const float* __restrict__ q, const float* __restrict__ Wl,
    const float* __restrict__ Wr, const float* __restrict__ a,
    uint4* __restrict__ glg, _Float16* __restrict__ gr16,
    unsigned short* __restrict__ grT_bf,
    float* __restrict__ AL, float* __restrict__ AR) {
  const int bl0 = blockIdx.x * 8;        // 512 blocks, no batch straddle
  const int b = bl0 >> 10;
  const int t = threadIdx.x;
  __shared__ __align__(16) float qs[8 * CC];           // 4 KB
  __shared__ __align__(16) unsigned short trT[DD][8];  // 1 KB
  __shared__ __align__(16) _Float16 trL[8][DD];        // 1 KB

  ((float4*)qs)[t] = ((const float4*)(q + (size_t)bl0 * CC))[t];
  __syncthreads();

  const int rr = t >> 6;                 // 0..3 -> rows rr*2, rr*2+1
  const int d  = t & 63;
  const int r0 = rr * 2, r1 = rr * 2 + 1;
  const float* q0 = qs + r0 * CC;
  const float* q1 = qs + r1 * CC;

  float aL0 = 0, aL1 = 0, aR0 = 0, aR1 = 0;
  float bL0 = 0, bL1 = 0, bR0 = 0, bR1 = 0;
#pragma unroll 8
  for (int c = 0; c < CC; c += 2) {
    float wl0 = Wl[c * DD + d],       wr0 = Wr[c * DD + d];
    float wl1 = Wl[(c + 1) * DD + d], wr1 = Wr[(c + 1) * DD + d];
    aL0 = fmaf(q0[c], wl0, aL0);  bL0 = fmaf(q0[c + 1], wl1, bL0);
    aL1 = fmaf(q1[c], wl0, aL1);  bL1 = fmaf(q1[c + 1], wl1, bL1);
    aR0 = fmaf(q0[c], wr0, aR0);  bR0 = fmaf(q0[c + 1], wr1, bR0);
    aR1 = fmaf(q1[c], wr0, aR1);  bR1 = fmaf(q1[c + 1], wr1, bR1);
  }
  float gL0 = aL0 + bL0, gL1 = aL1 + bL1;
  float gR0 = aR0 + bR0, gR1 = aR1 + bR1;

  trL[r0][d] = (_Float16)gL0;
  trL[r1][d] = (_Float16)gL1;
  gr16[(size_t)(bl0 + r0) * DD + d] = (_Float16)gR0;
  gr16[(size_t)(bl0 + r1) * DD + d] = (_Float16)gR1;
  trT[d][r0] = bf16rne(gR0);
  trT[d][r1] = bf16rne(gR1);

  float av = a[d];
  float vL0 = av * gL0, vL1 = av * gL1, vR0 = av * gR0, vR1 = av * gR1;
#pragma unroll
  for (int off = 1; off < 64; off <<= 1) {
    vL0 += __shfl_xor(vL0, off, 64);
    vL1 += __shfl_xor(vL1, off, 64);
    vR0 += __shfl_xor(vR0, off, 64);
    vR1 += __shfl_xor(vR1, off, 64);
  }
  if (d == 0) {
    AL[bl0 + r0] = vL0; AL[bl0 + r1] = vL1;
    AR[bl0 + r0] = vR0; AR[bl0 + r1] = vR1;
  }
  __syncthreads();
  if (t < 64) {
    // grT_bf[b][d=t][y = bl0..bl0+7] : 8 bf16 = 16 B
    *(uint4*)&grT_bf[(((size_t)(b * 64 + t)) << 10) + (bl0 & 1023)] =
        *(const uint4*)&trT[t][0];
  } else if (t < 128) {
    int tt = t - 64;
    int r = tt >> 3, g = tt & 7;       // row r, granule g (d = 8g..8g+7)
    glg[(((size_t)(b * 8 + g)) << 10) + (bl0 & 1023) + r] =
        *(const uint4*)&trL[r][g * 8];
  }
}

// ---------------------------------------------------------------------------
// k_fused: block = 8 x-rows, 512 threads, grid 512, 2 blocks/CU.
//  pass 1 (lane-owns-y): gl f16 pairs from glg straight to VGPRs (coalesced,
//    L2-hot); gr rows in 1 KB LDS (256 uints staged by t<256); a packed-f16
//    in SGPRs (32 pairs covering a[0..63]). Inner op = pk_add_f16 + and +
//    v_dot2_f32_f16 (1.5 instr/elem).
//  softmax: exact 2-phase, wave shuffles + tiny cross-wave LDS reduce.
//  P: fp32 scores (nontemporal) + packed bf16 frag tile in LDS (8 rows/kc).
//  pass 2: PV via mfma_f32_16x16x32_bf16; B-frags from grT_bf (L2-hot).
//    Validated lane maps: A l:[m=l&15][k=(l>>4)*8+j]; B l:[k][n=l&15];
//    D: row m=(l>>4)*4+i, col n=l&15. Rows m>=8 garbage, never read.
// ---------------------------------------------------------------------------
__global__ __launch_bounds__(512, 4) void k_fused(
    const uint4* __restrict__ glg, const _Float16* __restrict__ gr16,
    const unsigned short* __restrict__ grT_bf,
    const float* __restrict__ AL, const float* __restrict__ AR,
    const float* __restrict__ a,
    float* __restrict__ scores, float* __restrict__ yout) {
  const int bl0 = blockIdx.x * 8;        // 512 blocks
  const int b = bl0 >> 10;
  const int t = threadIdx.x;             // 0..511
  const int w = t >> 6, l = t & 63;

  __shared__ __align__(16) _Float16 grL[8 * DD];        // 1 KB = 256 uints
  __shared__ __align__(16) unsigned short eb[8704];     // 17 KB P frags
  __shared__ __align__(16) float sPV[8][4][8][17];      // 17 KB
  __shared__ float sM[8][8], sS[8][8], sFinM[8], sFinIS[8];

  // stage gr rows into LDS: 8 rows x 64 f16 = 512 f16 = 256 uints
  if (t < 256)
    ((unsigned*)grL)[t] = ((const unsigned*)(gr16 + (size_t)bl0 * DD))[t];

  // a -> 32 packed-f16 pairs in SGPRs (covers a[0..63])
  unsigned sa[32];
#pragma unroll
  for (int k = 0; k < 16; ++k) {
    float4 av = *(const float4*)&a[k * 4];
    union { hf2 h; unsigned u; } u0, u1;
    u0.h.x = (_Float16)av.x; u0.h.y = (_Float16)av.y;
    u1.h.x = (_Float16)av.z; u1.h.y = (_Float16)av.w;
    sa[k * 2]     = rflu(u0.u);
    sa[k * 2 + 1] = rflu(u1.u);
  }

  float pr[8];
#pragma unroll
  for (int x = 0; x < 8; ++x) pr[x] = C1H * rflf(AR[bl0 + x]);

  float alv[2];
  alv[0] = AL[b * LL + t];
  alv[1] = AL[b * LL + 512 + t];

  float pacc[8][2];
#pragma unroll
  for (int x = 0; x < 8; ++x) { pacc[x][0] = 0.f; pacc[x][1] = 0.f; }

  __syncthreads();                       // grL ready

  // ---- pass 1: e in registers, dblk-outer (16 d per dblk) ----
#pragma unroll
  for (int dblk = 0; dblk < 4; ++dblk) {
    uint4 gv[2][2];
#pragma unroll
    for (int yc = 0; yc < 2; ++yc)
#pragma unroll
      for (int g2 = 0; g2 < 2; ++g2)
        gv[yc][g2] =
            glg[(((size_t)(b * 8 + dblk * 2 + g2)) << 10) + yc * 512 + t];
#pragma unroll
    for (int x = 0; x < 8; ++x) {
      uint4 gra = *(const uint4*)&grL[x * DD + dblk * 16];      // d 0..7
      uint4 grb = *(const uint4*)&grL[x * DD + dblk * 16 + 8];  // d 8..15
#pragma unroll
      for (int yc = 0; yc < 2; ++yc) {
        float s = pacc[x][yc];
        s = dot2abs(gv[yc][0].x, gra.x, sa[dblk * 8 + 0], s);
        s = dot2abs(gv[yc][0].y, gra.y, sa[dblk * 8 + 1], s);
        s = dot2abs(gv[yc][0].z, gra.z, sa[dblk * 8 + 2], s);
        s = dot2abs(gv[yc][0].w, gra.w, sa[dblk * 8 + 3], s);
        s = dot2abs(gv[yc][1].x, grb.x, sa[dblk * 8 + 4], s);
        s = dot2abs(gv[yc][1].y, grb.y, sa[dblk * 8 + 5], s);
        s = dot2abs(gv[yc][1].z, grb.z, sa[dblk * 8 + 6], s);
        s = dot2abs(gv[yc][1].w, grb.w, sa[dblk * 8 + 7], s);
        pacc[x][yc] = s;
      }
    }
  }

  float ev[8][2];
#pragma unroll
  for (int x = 0; x < 8; ++x)
#pragma unroll
    for (int yc = 0; yc < 2; ++yc)
      ev[x][yc] = fmaf(C2H, pacc[x][yc], pr[x] + C1H * alv[yc]);

  // ---- exact softmax: max phase ----
  float lm[8];
#pragma unroll
  for (int x = 0; x < 8; ++x) lm[x] = fmaxf(ev[x][0], ev[x][1]);
#pragma unroll
  for (int off = 1; off < 64; off <<= 1) {
#pragma unroll
    for (int x = 0; x < 8; ++x) lm[x] = fmaxf(lm[x], __shfl_xor(lm[x], off, 64));
  }
  if (l == 0) {
#pragma unroll
    for (int x = 0; x < 8; ++x) sM[w][x] = lm[x];
  }
  __syncthreads();                       // barrier 2
  if (t < 64) {
    int x = t >> 3;
    float v = sM[t & 7][x];
    v = fmaxf(v, __shfl_xor(v, 1, 64));
    v = fmaxf(v, __shfl_xor(v, 2, 64));
    v = fmaxf(v, __shfl_xor(v, 4, 64));
    if ((t & 7) == 0) sFinM[x] = v;
  }
  __syncthreads();                       // barrier 3

  float mfin[8], lsum[8];
#pragma unroll
  for (int x = 0; x < 8; ++x) mfin[x] = sFinM[x];
#pragma unroll
  for (int x = 0; x < 8; ++x) {
    ev[x][0] = __expf(ev[x][0] - mfin[x]);
    ev[x][1] = __expf(ev[x][1] - mfin[x]);
    lsum[x] = ev[x][0] + ev[x][1];
  }
#pragma unroll
  for (int off = 1; off < 64; off <<= 1) {
#pragma unroll
    for (int x = 0; x < 8; ++x) lsum[x] += __shfl_xor(lsum[x], off, 64);
  }
  if (l == 0) {
#pragma unroll
    for (int x = 0; x < 8; ++x) sS[w][x] = lsum[x];
  }
  __syncthreads();                       // barrier 4
  if (t < 64) {
    int x = t >> 3;
    float v = sS[t & 7][x];
    v += __shfl_xor(v, 1, 64);
    v += __shfl_xor(v, 2, 64);
    v += __shfl_xor(v, 4, 64);
    if ((t & 7) == 0) sFinIS[x] = 1.0f / v;
  }
  __syncthreads();                       // barrier 5

  float isv[8];
#pragma unroll
  for (int x = 0; x < 8; ++x) isv[x] = sFinIS[x];

  // ---- P writes: fp32 scores (nontemporal) + packed bf16 frag tile ----
#pragma unroll
  for (int yc = 0; yc < 2; ++yc) {
    int y = yc * 512 + t;
    int kc = y >> 5, k32 = t & 31;
#pragma unroll
    for (int x = 0; x < 8; ++x) {
      float p = ev[x][yc] * isv[x];
      __builtin_nontemporal_store(p, &scores[((size_t)(bl0 + x) << 10) + y]);
      eb[kc * 256 + x * 32 + k32] = bf16rne(p);
    }
  }
  __syncthreads();                       // barrier 6

  // ---- pass 2: PV via MFMA, kc split across 8 waves ----
  f32x4 acc[4] = {{0.f, 0.f, 0.f, 0.f}, {0.f, 0.f, 0.f, 0.f},
                  {0.f, 0.f, 0.f, 0.f}, {0.f, 0.f, 0.f, 0.f}};
  const int row16 = l & 15, hh = l >> 4;
  const size_t bnBase = ((size_t)b * 64) << 10;
#pragma unroll
  for (int kk = 0; kk < 4; ++kk) {
    int kc = w * 4 + kk;
    bf16x8 af = *(const bf16x8*)&eb[kc * 256 + row16 * 32 + hh * 8];
#pragma unroll
    for (int nt = 0; nt < 4; ++nt) {
      bf16x8 bfv = *(const bf16x8*)(grT_bf + bnBase +
                     (((size_t)(nt * 16 + row16)) << 10) + kc * 32 + hh * 8);
      acc[nt] = __builtin_amdgcn_mfma_f32_16x16x32_bf16(af, bfv, acc[nt], 0, 0, 0);
    }
  }
  if (l < 32) {
#pragma unroll
    for (int nt = 0; nt < 4; ++nt)
#pragma unroll
      for (int i = 0; i < 4; ++i)
        sPV[w][nt][hh * 4 + i][row16] = acc[nt][i];
  }
  __syncthreads();                       // barrier 7
  {
    int x = t >> 6, dcol = t & 63, nt = dcol >> 4, col = dcol & 15;
    float r = 0.f;
#pragma unroll
    for (int ww = 0; ww < 8; ++ww) r += sPV[ww][nt][x][col];
    yout[(size_t)(bl0 + x) * DD + dcol] = r;
  }
}

// ---------------------------------------------------------------------------
extern "C" void kernel_launch(void* const* d_in, const int* in_sizes, int n_in,
                              void* d_out, int out_size, void* d_ws, size_t ws_size,
                              hipStream_t stream) {
  const float* q  = (const float*)d_in[0];
  // d_in[1] = keys, d_in[2] = values: unused by the reference math
  const float* Wl = (const float*)d_in[3];
  const float* Wr = (const float*)d_in[4];
  const float* a  = (const float*)d_in[5];

  float* yout = (float*)d_out;                 // (4096, 64)
  float* esc  = yout + NROW * DD;              // (4096, 1024) scores

  float* ws = (float*)d_ws;
  float* AL = ws;                               // 4096 f32
  float* AR = AL + NROW;                        // 4096 f32
  uint4* glg = (uint4*)(AR + NROW);             // 4096*8 uint4 (512 KB)
  _Float16* gr16 = (_Float16*)(glg + (size_t)NROW * 8);        // 512 KB
  unsigned short* grT_bf = (unsigned short*)(gr16 + (size_t)NROW * DD); // 512 KB

  k_proj <<<NROW / 8, 256, 0, stream>>>(q, Wl, Wr, a, glg, gr16, grT_bf, AL, AR);
  k_fused<<<NROW / 8, 512, 0, stream>>>(glg, gr16, grT_bf, AL, AR, a, esc, yout);
}